// Round 3
// baseline (903.154 us; speedup 1.0000x reference)
//
#include <hip/hip_runtime.h>
#include <hip/hip_bf16.h>
#include <math.h>

#define NNODES 100000
#define NEDGES 1600000
#define EPLUS  (NEDGES + NNODES)   // edges + self loops
#define INF    128
#define HF     64
#define NEG_SLOPE 0.2f
#define NB1 391                     // ceil(NNODES/256)

// ---- build int32 edge lists with self-loops appended; zero cnt ----
__global__ void k_edges(const int* __restrict__ ei, int* __restrict__ s32, int* __restrict__ d32,
                        int* __restrict__ cnt) {
    int i = blockIdx.x * blockDim.x + threadIdx.x;
    if (i < NNODES) cnt[i] = 0;
    if (i >= EPLUS) return;
    if (i < NEDGES) { s32[i] = ei[i]; d32[i] = ei[NEDGES + i]; }
    else            { s32[i] = i - NEDGES; d32[i] = i - NEDGES; }
}

__global__ void k_count(const int* __restrict__ d32, int* __restrict__ cnt) {
    int i = blockIdx.x * blockDim.x + threadIdx.x;
    if (i >= EPLUS) return;
    atomicAdd(&cnt[d32[i]], 1);
}

// ---- 3-kernel exclusive scan of cnt[N] -> roff[N] ----
__global__ __launch_bounds__(256) void k_scan_block(const int* __restrict__ cnt,
        int* __restrict__ roff, int* __restrict__ bsum) {
    __shared__ int sm[256];
    const int t = threadIdx.x;
    int i = blockIdx.x * 256 + t;
    int v = (i < NNODES) ? cnt[i] : 0;
    sm[t] = v; __syncthreads();
    #pragma unroll
    for (int o = 1; o < 256; o <<= 1) {
        int x = (t >= o) ? sm[t - o] : 0; __syncthreads();
        sm[t] += x; __syncthreads();
    }
    if (i < NNODES) roff[i] = sm[t] - v;     // exclusive within block
    if (t == 255) bsum[blockIdx.x] = sm[255];
}

__global__ __launch_bounds__(512) void k_scan_top(const int* __restrict__ bsum, int* __restrict__ boff) {
    __shared__ int sm[512];
    const int t = threadIdx.x;
    int v = (t < NB1) ? bsum[t] : 0;
    sm[t] = v; __syncthreads();
    #pragma unroll
    for (int o = 1; o < 512; o <<= 1) {
        int x = (t >= o) ? sm[t - o] : 0; __syncthreads();
        sm[t] += x; __syncthreads();
    }
    if (t < NB1) boff[t] = sm[t] - v;
}

__global__ __launch_bounds__(256) void k_scan_add(int* __restrict__ roff,
        const int* __restrict__ boff, int* __restrict__ woff) {
    int i = blockIdx.x * 256 + threadIdx.x;
    if (i < NNODES) { int r = roff[i] + boff[blockIdx.x]; roff[i] = r; woff[i] = r; }
    if (i == 0) roff[NNODES] = EPLUS;
}

__global__ void k_scatter(const int* __restrict__ s32, const int* __restrict__ d32,
                          int* __restrict__ woff, int* __restrict__ csr) {
    int i = blockIdx.x * blockDim.x + threadIdx.x;
    if (i >= EPLUS) return;
    int d = d32[i];
    int pos = atomicAdd(&woff[d], 1);
    csr[pos] = s32[i];
}

// ---- register-tiled GEMM transform: H = X@W, ls = H@asrc, ld = H@adst ----
// Block: 256 threads -> 64-node x 64-feature tile; thread: 4x4 register tile.
// X chunk staged transposed in LDS (XT[k][n], padded). In-place X==H safe:
// each block reads only its own 64 rows (all K) before writing them.
template<int IN>
__global__ __launch_bounds__(256) void k_transform(const float* __restrict__ X,
        const float* __restrict__ W, const float* __restrict__ asrc, const float* __restrict__ adst,
        float* __restrict__ H, float* __restrict__ ls, float* __restrict__ ld) {
    __shared__ float Wl[IN * HF];     // 32 KB (IN=128) / 16 KB (IN=64)
    __shared__ float XT[32][68];      // 8.7 KB, stride 68 keeps float4 alignment (272B)
    __shared__ float lssm[64], ldsm[64];
    const int t = threadIdx.x;
    for (int i = t * 4; i < IN * HF; i += 1024) *(float4*)&Wl[i] = *(const float4*)&W[i];
    const int n0 = (t & 15) * 4;      // node offset in tile
    const int f0 = (t >> 4) * 4;      // feature offset
    const float4 av = *(const float4*)&asrc[f0];
    const float4 dv = *(const float4*)&adst[f0];

    const int nb = blockIdx.x * 64;
    if (nb >= NNODES) return;

    float acc[4][4] = {};
    for (int kc = 0; kc < IN; kc += 32) {
        __syncthreads();              // orders Wl load / prev-iter XT reads
        #pragma unroll
        for (int it = 0; it < 2; ++it) {
            int i = t + it * 256;
            int r = i >> 3, c4 = i & 7;
            long long nrow = nb + r;
            float4 xv = make_float4(0.f, 0.f, 0.f, 0.f);
            if (nrow < NNODES) xv = *(const float4*)&X[nrow * IN + kc + c4 * 4];
            XT[c4 * 4 + 0][r] = xv.x;
            XT[c4 * 4 + 1][r] = xv.y;
            XT[c4 * 4 + 2][r] = xv.z;
            XT[c4 * 4 + 3][r] = xv.w;
        }
        __syncthreads();
        #pragma unroll
        for (int k = 0; k < 32; ++k) {
            float4 xv = *(const float4*)&XT[k][n0];
            float4 wv = *(const float4*)&Wl[(kc + k) * HF + f0];
            float xa[4] = {xv.x, xv.y, xv.z, xv.w};
            float wa[4] = {wv.x, wv.y, wv.z, wv.w};
            #pragma unroll
            for (int i = 0; i < 4; ++i)
                #pragma unroll
                for (int j = 0; j < 4; ++j)
                    acc[i][j] += xa[i] * wa[j];
        }
    }

    __syncthreads();
    if (t < 64) { lssm[t] = 0.f; ldsm[t] = 0.f; }
    __syncthreads();
    #pragma unroll
    for (int i = 0; i < 4; ++i) {
        float hs = acc[i][0] * av.x + acc[i][1] * av.y + acc[i][2] * av.z + acc[i][3] * av.w;
        float hd = acc[i][0] * dv.x + acc[i][1] * dv.y + acc[i][2] * dv.z + acc[i][3] * dv.w;
        atomicAdd(&lssm[n0 + i], hs);
        atomicAdd(&ldsm[n0 + i], hd);
        long long nrow = nb + n0 + i;
        if (nrow < NNODES)
            *(float4*)&H[nrow * HF + f0] = make_float4(acc[i][0], acc[i][1], acc[i][2], acc[i][3]);
    }
    __syncthreads();
    if (t < 64 && nb + t < NNODES) { ls[nb + t] = lssm[t]; ld[nb + t] = ldsm[t]; }
}

// ---- CSR aggregation: wave per dst node, lane = feature, online softmax ----
template<int FUSE_CLS>
__global__ __launch_bounds__(256) void k_gat(const int* __restrict__ roff, const int* __restrict__ csr,
        const float* __restrict__ ls, const float* __restrict__ ld, const float* __restrict__ H,
        const float* __restrict__ b, float* __restrict__ outX,
        const float* __restrict__ Wc, const float* __restrict__ bc, float* __restrict__ outC) {
    int n = blockIdx.x * 4 + (threadIdx.x >> 6);
    if (n >= NNODES) return;
    const int lane = threadIdx.x & 63;
    const int r0 = roff[n], r1 = roff[n + 1];
    const float ldv = ld[n];
    float m = -INFINITY, den = 0.f, acc = 0.f;
    for (int base = r0; base < r1; base += 64) {
        const int nb = min(64, r1 - base);
        const bool ok = (base + lane < r1);
        int  sv  = ok ? csr[base + lane] : 0;
        float lv = ok ? ls[sv] : 0.f;
        for (int j = 0; j < nb; ++j) {
            int s   = __shfl(sv, j);
            float e = __shfl(lv, j) + ldv;
            e = e > 0.f ? e : NEG_SLOPE * e;
            float mn    = fmaxf(m, e);
            float scale = __expf(m - mn);     // first iter: exp(-inf)=0
            float p     = __expf(e - mn);
            den = den * scale + p;
            acc = acc * scale + p * H[(long long)s * HF + lane];
            m = mn;
        }
    }
    float v = acc / (den + 1e-16f) + b[lane];
    v = fmaxf(v, 0.f);
    if (!FUSE_CLS) {
        outX[(long long)n * HF + lane] = v;
    } else {
        float a0 = v * Wc[lane * 2 + 0];
        float a1 = v * Wc[lane * 2 + 1];
        #pragma unroll
        for (int o = 32; o; o >>= 1) { a0 += __shfl_xor(a0, o); a1 += __shfl_xor(a1, o); }
        if (lane == 0) { outC[n * 2 + 0] = a0 + bc[0]; outC[n * 2 + 1] = a1 + bc[1]; }
    }
}

extern "C" void kernel_launch(void* const* d_in, const int* in_sizes, int n_in,
                              void* d_out, int out_size, void* d_ws, size_t ws_size,
                              hipStream_t stream) {
    const float* x      = (const float*)d_in[0];
    const int*   ei     = (const int*)d_in[1];
    const float* W0     = (const float*)d_in[2];
    const float* asrc0  = (const float*)d_in[3];
    const float* adst0  = (const float*)d_in[4];
    const float* b0     = (const float*)d_in[5];
    const float* Ws     = (const float*)d_in[6];
    const float* asrcs  = (const float*)d_in[7];
    const float* adsts  = (const float*)d_in[8];
    const float* bs     = (const float*)d_in[9];
    const float* Wc     = (const float*)d_in[10];
    const float* bc     = (const float*)d_in[11];
    float* out = (float*)d_out;

    // workspace layout (~74 MB)
    float* Hb   = (float*)d_ws;                    // N*64
    float* P    = Hb + (long long)NNODES * HF;     // N*64
    float* ls   = P + (long long)NNODES * HF;      // N
    float* ld   = ls + NNODES;                     // N
    int* s32    = (int*)(ld + NNODES);             // EPLUS
    int* d32    = s32 + EPLUS;                     // EPLUS
    int* csr    = d32 + EPLUS;                     // EPLUS
    int* cnt    = csr + EPLUS;                     // N
    int* roff   = cnt + NNODES;                    // N+1
    int* woff   = roff + NNODES + 1;               // N
    int* bsum   = woff + NNODES;                   // NB1
    int* boff   = bsum + NB1;                      // NB1

    const int B = 256;
    const int gEdges = (EPLUS + B - 1) / B;
    const int gNodeB = NB1;
    const int gNode4 = (NNODES + 3) / 4;
    const int gT     = (NNODES + 63) / 64;

    // ---- CSR build (once; reused by all 3 layers) ----
    k_edges<<<gEdges, B, 0, stream>>>(ei, s32, d32, cnt);
    k_count<<<gEdges, B, 0, stream>>>(d32, cnt);
    k_scan_block<<<gNodeB, B, 0, stream>>>(cnt, roff, bsum);
    k_scan_top<<<1, 512, 0, stream>>>(bsum, boff);
    k_scan_add<<<gNodeB, B, 0, stream>>>(roff, boff, woff);
    k_scatter<<<gEdges, B, 0, stream>>>(s32, d32, woff, csr);

    // ---- layer 0: x(128) -> Hb(h) -> P(x1) ----
    k_transform<INF><<<gT, B, 0, stream>>>(x, W0, asrc0, adst0, Hb, ls, ld);
    k_gat<0><<<gNode4, B, 0, stream>>>(roff, csr, ls, ld, Hb, b0, P, nullptr, nullptr, nullptr);

    // ---- layer 1: P -> P(h, in-place) -> Hb(x2) ----
    k_transform<HF><<<gT, B, 0, stream>>>(P, Ws + 0 * HF * HF, asrcs + 0 * HF, adsts + 0 * HF, P, ls, ld);
    k_gat<0><<<gNode4, B, 0, stream>>>(roff, csr, ls, ld, P, bs + 0 * HF, Hb, nullptr, nullptr, nullptr);

    // ---- layer 2: Hb -> Hb(h, in-place) -> fused classifier -> out ----
    k_transform<HF><<<gT, B, 0, stream>>>(Hb, Ws + 1 * HF * HF, asrcs + 1 * HF, adsts + 1 * HF, Hb, ls, ld);
    k_gat<1><<<gNode4, B, 0, stream>>>(roff, csr, ls, ld, Hb, bs + 1 * HF, nullptr, Wc, bc, out);
}

// Round 4
// 557.942 us; speedup vs baseline: 1.6187x; 1.6187x over previous
//
#include <hip/hip_runtime.h>
#include <hip/hip_bf16.h>
#include <math.h>

#define NNODES 100000
#define NEDGES 1600000
#define EPLUS  (NEDGES + NNODES)   // edges + self loops
#define INF    128
#define HF     64
#define NEG_SLOPE 0.2f
#define NB1 391                     // ceil(NNODES/256)

// ---- build int32 edge lists with self-loops appended; zero cnt ----
__global__ void k_edges(const int* __restrict__ ei, int* __restrict__ s32, int* __restrict__ d32,
                        int* __restrict__ cnt) {
    int i = blockIdx.x * blockDim.x + threadIdx.x;
    if (i < NNODES) cnt[i] = 0;
    if (i >= EPLUS) return;
    if (i < NEDGES) { s32[i] = ei[i]; d32[i] = ei[NEDGES + i]; }
    else            { s32[i] = i - NEDGES; d32[i] = i - NEDGES; }
}

__global__ void k_count(const int* __restrict__ d32, int* __restrict__ cnt) {
    int i = blockIdx.x * blockDim.x + threadIdx.x;
    if (i >= EPLUS) return;
    atomicAdd(&cnt[d32[i]], 1);
}

// ---- 3-kernel exclusive scan of cnt[N] -> roff[N] ----
__global__ __launch_bounds__(256) void k_scan_block(const int* __restrict__ cnt,
        int* __restrict__ roff, int* __restrict__ bsum) {
    __shared__ int sm[256];
    const int t = threadIdx.x;
    int i = blockIdx.x * 256 + t;
    int v = (i < NNODES) ? cnt[i] : 0;
    sm[t] = v; __syncthreads();
    #pragma unroll
    for (int o = 1; o < 256; o <<= 1) {
        int x = (t >= o) ? sm[t - o] : 0; __syncthreads();
        sm[t] += x; __syncthreads();
    }
    if (i < NNODES) roff[i] = sm[t] - v;     // exclusive within block
    if (t == 255) bsum[blockIdx.x] = sm[255];
}

__global__ __launch_bounds__(512) void k_scan_top(const int* __restrict__ bsum, int* __restrict__ boff) {
    __shared__ int sm[512];
    const int t = threadIdx.x;
    int v = (t < NB1) ? bsum[t] : 0;
    sm[t] = v; __syncthreads();
    #pragma unroll
    for (int o = 1; o < 512; o <<= 1) {
        int x = (t >= o) ? sm[t - o] : 0; __syncthreads();
        sm[t] += x; __syncthreads();
    }
    if (t < NB1) boff[t] = sm[t] - v;
}

__global__ __launch_bounds__(256) void k_scan_add(int* __restrict__ roff,
        const int* __restrict__ boff, int* __restrict__ woff) {
    int i = blockIdx.x * 256 + threadIdx.x;
    if (i < NNODES) { int r = roff[i] + boff[blockIdx.x]; roff[i] = r; woff[i] = r; }
    if (i == 0) roff[NNODES] = EPLUS;
}

__global__ void k_scatter(const int* __restrict__ s32, const int* __restrict__ d32,
                          int* __restrict__ woff, int* __restrict__ csr) {
    int i = blockIdx.x * blockDim.x + threadIdx.x;
    if (i >= EPLUS) return;
    int d = d32[i];
    int pos = atomicAdd(&woff[d], 1);
    csr[pos] = s32[i];
}

// ---- transform: H = X@W, ls = H@asrc, ld = H@adst ----
// Block = 256 threads = 64 nodes x 4 feature-groups (16 feats each).
// Thread: acc[16], statically indexed -> ~50 VGPR, no spills.
// X tile [64][65] in LDS (pad -> 2-way conflict = free), K chunked by 64.
// W in LDS, wave-uniform broadcast float4 reads.
// In-place X==H safe: block stages all K of its own 64 rows before writing.
template<int IN>
__global__ __launch_bounds__(256) void k_transform(const float* __restrict__ X,
        const float* __restrict__ W, const float* __restrict__ asrc, const float* __restrict__ adst,
        float* __restrict__ H, float* __restrict__ ls, float* __restrict__ ld) {
    __shared__ float Wl[IN * HF];       // 32 KB (IN=128) / 16 KB (IN=64)
    __shared__ float Xs[64 * 65];       // 16.6 KB
    __shared__ float lssm[64], ldsm[64];
    const int t = threadIdx.x;
    for (int i = t * 4; i < IN * HF; i += 1024) *(float4*)&Wl[i] = *(const float4*)&W[i];

    const int nb = blockIdx.x * 64;
    const int nl = t & 63;              // local node (same set across the 4 waves)
    const int f0 = (t >> 6) * 16;       // wave-uniform feature group

    float acc[16] = {0.f,0.f,0.f,0.f,0.f,0.f,0.f,0.f,0.f,0.f,0.f,0.f,0.f,0.f,0.f,0.f};

    for (int kc = 0; kc < IN; kc += 64) {
        __syncthreads();                // Xs free (prev chunk) / Wl ready (1st)
        // stage 64 rows x 64 k: 1024 float4 over 256 threads, coalesced
        #pragma unroll
        for (int it = 0; it < 4; ++it) {
            int i = t + it * 256;
            int r = i >> 4, c = i & 15;
            float4 xv = make_float4(0.f, 0.f, 0.f, 0.f);
            if (nb + r < NNODES) xv = *(const float4*)&X[(long long)(nb + r) * IN + kc + c * 4];
            Xs[r * 65 + c * 4 + 0] = xv.x;
            Xs[r * 65 + c * 4 + 1] = xv.y;
            Xs[r * 65 + c * 4 + 2] = xv.z;
            Xs[r * 65 + c * 4 + 3] = xv.w;
        }
        __syncthreads();
        #pragma unroll 4
        for (int k = 0; k < 64; ++k) {
            float xk = Xs[nl * 65 + k];
            #pragma unroll
            for (int f4 = 0; f4 < 4; ++f4) {
                float4 wv = *(const float4*)&Wl[(kc + k) * HF + f0 + f4 * 4];
                acc[f4 * 4 + 0] += xk * wv.x;
                acc[f4 * 4 + 1] += xk * wv.y;
                acc[f4 * 4 + 2] += xk * wv.z;
                acc[f4 * 4 + 3] += xk * wv.w;
            }
        }
    }

    // epilogue: logits (cross-wave reduce via LDS) + H store
    if (t < 64) { lssm[t] = 0.f; ldsm[t] = 0.f; }
    __syncthreads();
    float hs = 0.f, hd = 0.f;
    #pragma unroll
    for (int f4 = 0; f4 < 4; ++f4) {
        float4 av = *(const float4*)&asrc[f0 + f4 * 4];
        float4 dv = *(const float4*)&adst[f0 + f4 * 4];
        hs += acc[f4*4+0]*av.x + acc[f4*4+1]*av.y + acc[f4*4+2]*av.z + acc[f4*4+3]*av.w;
        hd += acc[f4*4+0]*dv.x + acc[f4*4+1]*dv.y + acc[f4*4+2]*dv.z + acc[f4*4+3]*dv.w;
    }
    atomicAdd(&lssm[nl], hs);
    atomicAdd(&ldsm[nl], hd);
    if (nb + nl < NNODES) {
        #pragma unroll
        for (int f4 = 0; f4 < 4; ++f4)
            *(float4*)&H[(long long)(nb + nl) * HF + f0 + f4 * 4] =
                make_float4(acc[f4*4+0], acc[f4*4+1], acc[f4*4+2], acc[f4*4+3]);
    }
    __syncthreads();
    if (t < 64 && nb + t < NNODES) { ls[nb + t] = lssm[t]; ld[nb + t] = ldsm[t]; }
}

// ---- CSR aggregation: wave per dst node, lane = feature ----
// Tile-parallel softmax: wave max-reduce, ONE exp for 64 logits, sum-reduce,
// one rescale per tile; j-loop is independent gathers+FMA (2 accumulators).
template<int FUSE_CLS>
__global__ __launch_bounds__(256) void k_gat(const int* __restrict__ roff, const int* __restrict__ csr,
        const float* __restrict__ ls, const float* __restrict__ ld, const float* __restrict__ H,
        const float* __restrict__ b, float* __restrict__ outX,
        const float* __restrict__ Wc, const float* __restrict__ bc, float* __restrict__ outC) {
    int n = blockIdx.x * 4 + (threadIdx.x >> 6);
    if (n >= NNODES) return;
    const int lane = threadIdx.x & 63;
    const int r0 = roff[n], r1 = roff[n + 1];
    const float ldv = ld[n];
    float m = -INFINITY, den = 0.f, acc0 = 0.f, acc1 = 0.f;
    for (int base = r0; base < r1; base += 64) {
        const int nb = min(64, r1 - base);
        const bool ok = (lane < nb);
        int  sv = ok ? csr[base + lane] : 0;
        float e = ok ? (ls[sv] + ldv) : -INFINITY;
        e = e > 0.f ? e : NEG_SLOPE * e;          // -inf stays -inf
        float tm = e;
        #pragma unroll
        for (int o = 32; o; o >>= 1) tm = fmaxf(tm, __shfl_xor(tm, o));
        float mn = fmaxf(m, tm);                  // finite (tile has >=1 edge)
        float p  = __expf(e - mn);                // inactive lanes -> 0
        float ts = p;
        #pragma unroll
        for (int o = 32; o; o >>= 1) ts += __shfl_xor(ts, o);
        float scale = __expf(m - mn);             // first tile: exp(-inf)=0
        den  = den * scale + ts;
        acc0 *= scale; acc1 *= scale;
        int j = 0;
        for (; j + 1 < nb; j += 2) {
            int   s0 = __shfl(sv, j),     s1 = __shfl(sv, j + 1);
            float p0 = __shfl(p,  j),     p1 = __shfl(p,  j + 1);
            acc0 += p0 * H[(long long)s0 * HF + lane];
            acc1 += p1 * H[(long long)s1 * HF + lane];
        }
        if (j < nb) {
            int s0 = __shfl(sv, j); float p0 = __shfl(p, j);
            acc0 += p0 * H[(long long)s0 * HF + lane];
        }
        m = mn;
    }
    float v = (acc0 + acc1) / (den + 1e-16f) + b[lane];
    v = fmaxf(v, 0.f);
    if (!FUSE_CLS) {
        outX[(long long)n * HF + lane] = v;
    } else {
        float a0 = v * Wc[lane * 2 + 0];
        float a1 = v * Wc[lane * 2 + 1];
        #pragma unroll
        for (int o = 32; o; o >>= 1) { a0 += __shfl_xor(a0, o); a1 += __shfl_xor(a1, o); }
        if (lane == 0) { outC[n * 2 + 0] = a0 + bc[0]; outC[n * 2 + 1] = a1 + bc[1]; }
    }
}

extern "C" void kernel_launch(void* const* d_in, const int* in_sizes, int n_in,
                              void* d_out, int out_size, void* d_ws, size_t ws_size,
                              hipStream_t stream) {
    const float* x      = (const float*)d_in[0];
    const int*   ei     = (const int*)d_in[1];
    const float* W0     = (const float*)d_in[2];
    const float* asrc0  = (const float*)d_in[3];
    const float* adst0  = (const float*)d_in[4];
    const float* b0     = (const float*)d_in[5];
    const float* Ws     = (const float*)d_in[6];
    const float* asrcs  = (const float*)d_in[7];
    const float* adsts  = (const float*)d_in[8];
    const float* bs     = (const float*)d_in[9];
    const float* Wc     = (const float*)d_in[10];
    const float* bc     = (const float*)d_in[11];
    float* out = (float*)d_out;

    // workspace layout (~74 MB)
    float* Hb   = (float*)d_ws;                    // N*64
    float* P    = Hb + (long long)NNODES * HF;     // N*64
    float* ls   = P + (long long)NNODES * HF;      // N
    float* ld   = ls + NNODES;                     // N
    int* s32    = (int*)(ld + NNODES);             // EPLUS
    int* d32    = s32 + EPLUS;                     // EPLUS
    int* csr    = d32 + EPLUS;                     // EPLUS
    int* cnt    = csr + EPLUS;                     // N
    int* roff   = cnt + NNODES;                    // N+1
    int* woff   = roff + NNODES + 1;               // N
    int* bsum   = woff + NNODES;                   // NB1
    int* boff   = bsum + NB1;                      // NB1

    const int B = 256;
    const int gEdges = (EPLUS + B - 1) / B;
    const int gNodeB = NB1;
    const int gNode4 = (NNODES + 3) / 4;
    const int gT     = (NNODES + 63) / 64;

    // ---- CSR build (once; reused by all 3 layers) ----
    k_edges<<<gEdges, B, 0, stream>>>(ei, s32, d32, cnt);
    k_count<<<gEdges, B, 0, stream>>>(d32, cnt);
    k_scan_block<<<gNodeB, B, 0, stream>>>(cnt, roff, bsum);
    k_scan_top<<<1, 512, 0, stream>>>(bsum, boff);
    k_scan_add<<<gNodeB, B, 0, stream>>>(roff, boff, woff);
    k_scatter<<<gEdges, B, 0, stream>>>(s32, d32, woff, csr);

    // ---- layer 0: x(128) -> Hb(h) -> P(x1) ----
    k_transform<INF><<<gT, B, 0, stream>>>(x, W0, asrc0, adst0, Hb, ls, ld);
    k_gat<0><<<gNode4, B, 0, stream>>>(roff, csr, ls, ld, Hb, b0, P, nullptr, nullptr, nullptr);

    // ---- layer 1: P -> P(h, in-place) -> Hb(x2) ----
    k_transform<HF><<<gT, B, 0, stream>>>(P, Ws + 0 * HF * HF, asrcs + 0 * HF, adsts + 0 * HF, P, ls, ld);
    k_gat<0><<<gNode4, B, 0, stream>>>(roff, csr, ls, ld, P, bs + 0 * HF, Hb, nullptr, nullptr, nullptr);

    // ---- layer 2: Hb -> Hb(h, in-place) -> fused classifier -> out ----
    k_transform<HF><<<gT, B, 0, stream>>>(Hb, Ws + 1 * HF * HF, asrcs + 1 * HF, adsts + 1 * HF, Hb, ls, ld);
    k_gat<1><<<gNode4, B, 0, stream>>>(roff, csr, ls, ld, Hb, bs + 1 * HF, nullptr, Wc, bc, out);
}